// Round 10
// baseline (164.004 us; speedup 1.0000x reference)
//
#include <hip/hip_runtime.h>
#include <float.h>
#include <math.h>

// Problem constants (B=8, T=4096, D=128, K=2048)
#define NTOK 32768
#define DD 128
#define HH 64
#define KK 2048
#define NSLICE 8
#define TG_COUNT (NTOK / 64)          // 512 token groups (64 tokens/block)
#define NCHUNK 16                     // 16 one-tile chunks per slice (256 codes)

// d_out flat layout (all float32):
#define OFF_OUT 0
#define OFF_IDS (NTOK * HH)
#define OFF_COM (OFF_IDS + NTOK)
#define OFF_COD (OFF_COM + NTOK)

// ws layout (bytes)
#define WS_BP   ((size_t)0)                      // B tiles: 128 * 4096 = 524288
#define WS_ST2  (WS_BP + 524288)                 // (e2, stz) per code: 2048*8 = 16384
#define WS_C    (WS_ST2 + 16384)                 // C per token: 32768*4 = 131072
#define WS_CAND (WS_C + 131072)                  // cand: 8*NTOK*16 = 4194304
#define WS_LE   (WS_CAND + 4194304)
#define WS_B2   (WS_LE + (size_t)KK * 8)
#define WS_DEN  (WS_B2 + (size_t)KK * 8)
#define WS_NEED (WS_DEN + (size_t)KK * 8)        // ~4.92 MB

typedef short s16x8 __attribute__((ext_vector_type(8)));
typedef float f32x4 __attribute__((ext_vector_type(4)));

// ---- bf16 helpers (RNE) ----
static __device__ inline unsigned short f2bf(float v) {
    unsigned int u = __float_as_uint(v);
    unsigned int r = (u + 0x7FFFu + ((u >> 16) & 1u)) >> 16;
    return (unsigned short)r;
}
static __device__ inline float bf2f(unsigned short s) {
    return __uint_as_float(((unsigned int)s) << 16);
}
static __device__ inline unsigned short bf_hi(float v) { return f2bf(v); }
static __device__ inline unsigned short bf_lo(float v) { return f2bf(v - bf2f(f2bf(v))); }

// ===========================================================================
// prep_c: C[t] = sum(mu_i^2) + sum(exp(x_sig)) per token. Coalesced.
// ===========================================================================
__global__ __launch_bounds__(256) void prep_c(const float* __restrict__ x,
                                              float* __restrict__ Cg) {
    __shared__ float p_lds[64 * 33];
    const int tid = threadIdx.x;
    const float4* xb = (const float4*)x + (size_t)blockIdx.x * 2048;
#pragma unroll
    for (int i = 0; i < 8; ++i) {
        int fid = i * 256 + tid;
        float4 v = xb[fid];
        int r = fid >> 5, c = fid & 31;
        float p;
        if (c < 16) p = v.x * v.x + v.y * v.y + v.z * v.z + v.w * v.w;
        else        p = __expf(v.x) + __expf(v.y) + __expf(v.z) + __expf(v.w);
        p_lds[r * 33 + c] = p;
    }
    __syncthreads();
    if (tid < 64) {
        float s = 0.f;
#pragma unroll
        for (int c = 0; c < 32; ++c) s += p_lds[tid * 33 + c];
        Cg[blockIdx.x * 64 + tid] = s;
    }
}

// ===========================================================================
// prep_b: B tiles (4 planes: muHi[0:32], muHi[32:64], muLo[0:32], muLo[32:64])
// in MFMA fragment order + fp32 (e2, stz) + fp64 stats for exact rerank.
// d(t,k) = stz*(C_t - 2*dot) + e2   with e2 = 0.5*le + b2*stz.
// ===========================================================================
__global__ __launch_bounds__(256) void prep_b(const float* __restrict__ emb,
                                              unsigned short* __restrict__ Bp,
                                              float2* __restrict__ st2,
                                              double* __restrict__ Le,
                                              double* __restrict__ B2,
                                              double* __restrict__ Den) {
    int k = blockIdx.x * 256 + threadIdx.x;   // grid = KK/256
    const float* row = emb + (size_t)k * DD;
    float me[64];
    double le = 0.0, b2 = 0.0, se = 0.0;
#pragma unroll
    for (int h = 0; h < HH; ++h) {
        float m = row[h]; me[h] = m;
        b2 += (double)m * (double)m;
    }
#pragma unroll
    for (int h = 0; h < HH; ++h) {
        float u = row[HH + h];
        le += (double)u; se += exp((double)u);
    }
    const double stzd = 1.0 / (2.0 * se);
    const float stz = (float)stzd;
    const float e2  = (float)(0.5 * le + b2 * stzd);

    unsigned short* tb = Bp + (size_t)(k >> 4) * 2048;  // ushort units per 4KB tile
    const int col = k & 15;
#pragma unroll
    for (int g = 0; g < 4; ++g) {
        s16x8 o0, o1, o2, o3;
#pragma unroll
        for (int j = 0; j < 8; ++j) {
            int h = g * 8 + j;
            o0[j] = (short)bf_hi(me[h]);
            o1[j] = (short)bf_hi(me[32 + h]);
            o2[j] = (short)bf_lo(me[h]);
            o3[j] = (short)bf_lo(me[32 + h]);
        }
        int base = (g * 16 + col) * 8;
        *(s16x8*)(tb + 0 * 512 + base) = o0;
        *(s16x8*)(tb + 1 * 512 + base) = o1;
        *(s16x8*)(tb + 2 * 512 + base) = o2;
        *(s16x8*)(tb + 3 * 512 + base) = o3;
    }
    st2[k] = make_float2(e2, stz);
    Le[k] = le; B2[k] = b2; Den[k] = se;
}

// ===========================================================================
// vq_mfma: 4096 blocks (512 token-groups x 8 K-slices), 128 thr (2 waves).
// Both waves scan the full 256-code slice; wave = 32 tokens (2 A-sets).
// B fragments direct global->VGPR (L2-resident), 2-deep software prefetch.
// ===========================================================================
// top-2 update: 2 cmp + 3 cndmask + max + min (med3 form; D1<=D2 invariant)
#define TOP2(dv, kgv, D1, D2, I1, I2) do {                 \
        bool _c1 = (dv) < (D1); bool _c2 = (dv) < (D2);    \
        (I2) = _c1 ? (I1) : (_c2 ? (kgv) : (I2));          \
        (D2) = fminf(fmaxf((dv), (D1)), (D2));             \
        (D1) = fminf((dv), (D1));                          \
        (I1) = _c1 ? (kgv) : (I1);                         \
    } while (0)

#define LOADB(kt, B0, B1, B2v, B3v, ST) do {                       \
        const char* _p = bpc + (size_t)(kt) * 4096 + lane * 16;    \
        B0  = *(const s16x8*)(_p + 0 * 1024);                      \
        B1  = *(const s16x8*)(_p + 1 * 1024);                      \
        B2v = *(const s16x8*)(_p + 2 * 1024);                      \
        B3v = *(const s16x8*)(_p + 3 * 1024);                      \
        ST  = st2[(kt) * 16 + colv];                               \
    } while (0)

#define COMPUTE(B0, B1, B2v, B3v, ST, KG) do {                                       \
        f32x4 acc0 = {0.f, 0.f, 0.f, 0.f};                                           \
        f32x4 acc1 = {0.f, 0.f, 0.f, 0.f};                                           \
        acc0 = __builtin_amdgcn_mfma_f32_16x16x32_bf16(aH00, B0,  acc0, 0, 0, 0);    \
        acc1 = __builtin_amdgcn_mfma_f32_16x16x32_bf16(aH10, B0,  acc1, 0, 0, 0);    \
        acc0 = __builtin_amdgcn_mfma_f32_16x16x32_bf16(aH01, B1,  acc0, 0, 0, 0);    \
        acc1 = __builtin_amdgcn_mfma_f32_16x16x32_bf16(aH11, B1,  acc1, 0, 0, 0);    \
        acc0 = __builtin_amdgcn_mfma_f32_16x16x32_bf16(aH00, B2v, acc0, 0, 0, 0);    \
        acc1 = __builtin_amdgcn_mfma_f32_16x16x32_bf16(aH10, B2v, acc1, 0, 0, 0);    \
        acc0 = __builtin_amdgcn_mfma_f32_16x16x32_bf16(aH01, B3v, acc0, 0, 0, 0);    \
        acc1 = __builtin_amdgcn_mfma_f32_16x16x32_bf16(aH11, B3v, acc1, 0, 0, 0);    \
        acc0 = __builtin_amdgcn_mfma_f32_16x16x32_bf16(aL00, B0,  acc0, 0, 0, 0);    \
        acc1 = __builtin_amdgcn_mfma_f32_16x16x32_bf16(aL10, B0,  acc1, 0, 0, 0);    \
        acc0 = __builtin_amdgcn_mfma_f32_16x16x32_bf16(aL01, B1,  acc0, 0, 0, 0);    \
        acc1 = __builtin_amdgcn_mfma_f32_16x16x32_bf16(aL11, B1,  acc1, 0, 0, 0);    \
        const float _e2  = ST.x;                                                     \
        const float _stz = ST.y;                                                     \
        const int   _kg  = (KG);                                                     \
        _Pragma("unroll")                                                            \
        for (int r = 0; r < 4; ++r) {                                                \
            float u0 = fmaf(acc0[r], -2.0f, c40[r]);                                 \
            float dA = fmaf(_stz, u0, _e2);                                          \
            TOP2(dA, _kg, d1[0][r], d2[0][r], i1[0][r], i2[0][r]);                   \
            float u1 = fmaf(acc1[r], -2.0f, c41[r]);                                 \
            float dB = fmaf(_stz, u1, _e2);                                          \
            TOP2(dB, _kg, d1[1][r], d2[1][r], i1[1][r], i2[1][r]);                   \
        }                                                                            \
    } while (0)

static __device__ inline void mk_frag(float4 a, float4 b, s16x8& hi, s16x8& lo) {
    float f[8] = {a.x, a.y, a.z, a.w, b.x, b.y, b.z, b.w};
#pragma unroll
    for (int j = 0; j < 8; ++j) {
        hi[j] = (short)bf_hi(f[j]);
        lo[j] = (short)bf_lo(f[j]);
    }
}

__global__ __launch_bounds__(128) void vq_mfma(const float* __restrict__ x,
                                               const unsigned short* __restrict__ Bp,
                                               const float2* __restrict__ st2,
                                               const float* __restrict__ Cg,
                                               float4* __restrict__ cand) {
    const int tid  = threadIdx.x;
    const int lane = tid & 63;
    const int wid  = tid >> 6;                    // token half only
    const int tg    = blockIdx.x & (TG_COUNT - 1);
    const int slice = blockIdx.x >> 9;            // 0..7
    const int grp  = lane >> 4;
    const int colv = lane & 15;
    const char* bpc = (const char*)Bp;

    // ---- build A fragments (hi/lo) + per-row C, direct from global ----
    s16x8 aH00, aH01, aL00, aL01;    // set 0: tokens [0..15] of this wave's 32
    s16x8 aH10, aH11, aL10, aL11;    // set 1: tokens [16..31]
    f32x4 c40, c41;
    {
        const int hb = grp * 8;
        const float* xr0 = x + (size_t)(tg * 64 + wid * 32 + colv) * DD;
        const float* xr1 = xr0 + 16 * DD;
        float4 v0 = *(const float4*)(xr0 + hb);
        float4 v1 = *(const float4*)(xr0 + hb + 4);
        float4 v2 = *(const float4*)(xr0 + hb + 32);
        float4 v3 = *(const float4*)(xr0 + hb + 36);
        mk_frag(v0, v1, aH00, aL00);
        mk_frag(v2, v3, aH01, aL01);
        v0 = *(const float4*)(xr1 + hb);
        v1 = *(const float4*)(xr1 + hb + 4);
        v2 = *(const float4*)(xr1 + hb + 32);
        v3 = *(const float4*)(xr1 + hb + 36);
        mk_frag(v0, v1, aH10, aL10);
        mk_frag(v2, v3, aH11, aL11);
        c40 = *(const f32x4*)(Cg + tg * 64 + wid * 32 + grp * 4);
        c41 = *(const f32x4*)(Cg + tg * 64 + wid * 32 + 16 + grp * 4);
    }

    float d1[2][4], d2[2][4];
    int   i1[2][4], i2[2][4];
#pragma unroll
    for (int s = 0; s < 2; ++s)
#pragma unroll
        for (int r = 0; r < 4; ++r) {
            d1[s][r] = FLT_MAX; d2[s][r] = FLT_MAX; i1[s][r] = 0; i2[s][r] = 0;
        }

    // slice covers codes [slice*256, slice*256+256) = 16 tiles
    const int kt0 = slice * 16;
    const int kg0 = slice * 256 + colv;

    s16x8 pb0, pb1, pb2, pb3; float2 pst;
    s16x8 qb0, qb1, qb2, qb3; float2 qst;
    LOADB(kt0, pb0, pb1, pb2, pb3, pst);
#pragma unroll 1
    for (int c = 0; c < NCHUNK; c += 2) {
        LOADB(kt0 + c + 1, qb0, qb1, qb2, qb3, qst);          // prefetch odd chunk
        COMPUTE(pb0, pb1, pb2, pb3, pst, kg0 + c * 16);
        if (c + 2 < NCHUNK)
            LOADB(kt0 + c + 2, pb0, pb1, pb2, pb3, pst);      // prefetch next even
        COMPUTE(qb0, qb1, qb2, qb3, qst, kg0 + (c + 1) * 16);
    }

    // ---- merge top-2 across the 16 lanes of each row group ----
#pragma unroll
    for (int m = 1; m <= 8; m <<= 1) {
#pragma unroll
        for (int s = 0; s < 2; ++s)
#pragma unroll
            for (int r = 0; r < 4; ++r) {
                float od1 = __shfl_xor(d1[s][r], m, 64);
                int   oi1 = __shfl_xor(i1[s][r], m, 64);
                float od2 = __shfl_xor(d2[s][r], m, 64);
                int   oi2 = __shfl_xor(i2[s][r], m, 64);
                bool take = (od1 < d1[s][r]) || (od1 == d1[s][r] && oi1 < i1[s][r]);
                float rA = take ? d1[s][r] : od1;
                int  riA = take ? i1[s][r] : oi1;
                float rB = take ? od2 : d2[s][r];
                int  riB = take ? oi2 : i2[s][r];
                if (take) { d1[s][r] = od1; i1[s][r] = oi1; }
                bool t2 = (rA < rB) || (rA == rB && riA < riB);
                d2[s][r] = t2 ? rA : rB;
                i2[s][r] = t2 ? riA : riB;
            }
    }

    if (colv == 0) {
#pragma unroll
        for (int s = 0; s < 2; ++s)
#pragma unroll
            for (int r = 0; r < 4; ++r) {
                int tl = wid * 32 + s * 16 + grp * 4 + r;
                float4 o;
                o.x = d1[s][r]; o.y = d2[s][r];
                o.z = __int_as_float(i1[s][r]); o.w = __int_as_float(i2[s][r]);
                cand[(size_t)slice * NTOK + tg * 64 + tl] = o;
            }
    }
}

// ===========================================================================
// finalize: fp32 merge of 8 slice top-2's; threshold-gated exact fp64 rerank
// of all 16 candidates (rare); epilogue.
// ===========================================================================
static __device__ double dist64(const float* xr, const float* emb, int k, double Cv,
                                const double* Le, const double* B2, const double* Den) {
    const float4* er = (const float4*)(emb + (size_t)k * DD);
    const float4* xv = (const float4*)xr;
    double s0 = 0.0, s1 = 0.0;
#pragma unroll
    for (int j = 0; j < 16; ++j) {
        float4 e = er[j]; float4 xx = xv[j];
        s0 += (double)xx.x * (double)e.x + (double)xx.z * (double)e.z;
        s1 += (double)xx.y * (double)e.y + (double)xx.w * (double)e.w;
    }
    return 0.5 * Le[k] + (Cv + B2[k] - 2.0 * (s0 + s1)) / (2.0 * Den[k]);
}

__global__ __launch_bounds__(256) void finalize(const float* __restrict__ x,
                                                const float* __restrict__ emb,
                                                const float* __restrict__ z,
                                                const float4* __restrict__ cand,
                                                const double* __restrict__ Le,
                                                const double* __restrict__ B2,
                                                const double* __restrict__ Den,
                                                float* __restrict__ out) {
    __shared__ int   s_bid[64];
    __shared__ float s_ssd[64][4];
    const int tid = threadIdx.x;
    const int tb  = blockIdx.x * 64;

    if (tid < 64) {
        const int gt = tb + tid;
        float D1 = FLT_MAX, D2 = FLT_MAX;
        int   I1 = 0, I2 = 0;
        int   allk[2 * NSLICE];
#pragma unroll
        for (int s = 0; s < NSLICE; ++s) {
            float4 cd = cand[(size_t)s * NTOK + gt];
            float dA = cd.x; int iA = __float_as_int(cd.z);
            float dB = cd.y; int iB = __float_as_int(cd.w);
            allk[2 * s]     = iA;
            allk[2 * s + 1] = iB;
            bool t1 = (dA < D1) || (dA == D1 && iA < I1);
            float rA = t1 ? D1 : dA;  int riA = t1 ? I1 : iA;
            if (t1) { D1 = dA; I1 = iA; }
            bool t2 = (rA < D2) || (rA == D2 && riA < I2);
            if (t2) { D2 = rA; I2 = riA; }
            bool u1 = (dB < D1) || (dB == D1 && iB < I1);
            float rB = u1 ? D1 : dB;  int riB = u1 ? I1 : iB;
            if (u1) { D1 = dB; I1 = iB; }
            bool u2 = (rB < D2) || (rB == D2 && riB < I2);
            if (u2) { D2 = rB; I2 = riB; }
        }
        if (D2 - D1 < 3e-5f * (1.0f + fabsf(D1))) {
            // exact fp64 rerank over all 16 candidates with exact C
            const float* xr = x + (size_t)gt * DD;
            double C64 = 0.0;
            for (int h = 0; h < HH; ++h) { double m = (double)xr[h]; C64 += m * m; }
            for (int h = HH; h < DD; ++h) C64 += exp((double)xr[h]);
            double bd = 1e300; int bi = 0;
            for (int s = 0; s < 2 * NSLICE; ++s) {
                int k = allk[s];
                double dv = dist64(xr, emb, k, C64, Le, B2, Den);
                if (dv < bd || (dv == bd && k < bi)) { bd = dv; bi = k; }
            }
            I1 = bi;
        }
        s_bid[tid] = I1;
        out[OFF_IDS + gt] = (float)I1;
    }
    __syncthreads();

    // epilogue: 4 threads per token, 16 out-dims each
    {
        const int ltok = tid >> 2;
        const int q    = tid & 3;
        const int gt   = tb + ltok;
        const int code = s_bid[ltok];
        const float* er  = emb + (size_t)code * DD;
        const float* xr2 = x + (size_t)gt * DD;
        const float* zr  = z + (size_t)gt * HH;
        float ssd = 0.f;
#pragma unroll
        for (int j = 0; j < 4; ++j) {
            const int h0 = q * 16 + j * 4;
            float4 qm = *(const float4*)(er + h0);
            float4 xm = *(const float4*)(xr2 + h0);
            float4 qs = *(const float4*)(er + HH + h0);
            float4 xs = *(const float4*)(xr2 + HH + h0);
            float4 zv = *(const float4*)(zr + h0);
            float4 o;
            o.x = qm.x + __expf(0.5f * qs.x) * zv.x;
            o.y = qm.y + __expf(0.5f * qs.y) * zv.y;
            o.z = qm.z + __expf(0.5f * qs.z) * zv.z;
            o.w = qm.w + __expf(0.5f * qs.w) * zv.w;
            *(float4*)(out + OFF_OUT + (size_t)gt * HH + h0) = o;
            float dx, ds;
            dx = qm.x - xm.x; ssd += dx * dx;
            dx = qm.y - xm.y; ssd += dx * dx;
            dx = qm.z - xm.z; ssd += dx * dx;
            dx = qm.w - xm.w; ssd += dx * dx;
            ds = qs.x - xs.x; ssd += ds * ds;
            ds = qs.y - xs.y; ssd += ds * ds;
            ds = qs.z - xs.z; ssd += ds * ds;
            ds = qs.w - xs.w; ssd += ds * ds;
        }
        s_ssd[ltok][q] = ssd;
    }
    __syncthreads();

    if (tid < 64) {
        const int gt = tb + tid;
        float tot = s_ssd[tid][0] + s_ssd[tid][1] + s_ssd[tid][2] + s_ssd[tid][3];
        float mean = tot * (1.0f / 128.0f);
        out[OFF_COM + gt] = mean;
        out[OFF_COD + gt] = mean;
    }
}

// ---------------------------------------------------------------------------
extern "C" void kernel_launch(void* const* d_in, const int* in_sizes, int n_in,
                              void* d_out, int out_size, void* d_ws, size_t ws_size,
                              hipStream_t stream) {
    const float* x   = (const float*)d_in[0];
    const float* emb = (const float*)d_in[1];
    const float* z   = (const float*)d_in[2];
    float* out = (float*)d_out;

    unsigned short* Bp  = (unsigned short*)((char*)d_ws + WS_BP);
    float2* st2  = (float2*)((char*)d_ws + WS_ST2);
    float*  Cgl  = (float*)((char*)d_ws + WS_C);
    float4* cd   = (float4*)((char*)d_ws + WS_CAND);
    double* Le   = (double*)((char*)d_ws + WS_LE);
    double* B2   = (double*)((char*)d_ws + WS_B2);
    double* Den  = (double*)((char*)d_ws + WS_DEN);

    hipLaunchKernelGGL(prep_c, dim3(TG_COUNT), dim3(256), 0, stream, x, Cgl);
    hipLaunchKernelGGL(prep_b, dim3(KK / 256), dim3(256), 0, stream,
                       emb, Bp, st2, Le, B2, Den);
    hipLaunchKernelGGL(vq_mfma, dim3(TG_COUNT * NSLICE), dim3(128), 0, stream,
                       x, Bp, st2, Cgl, cd);
    hipLaunchKernelGGL(finalize, dim3(TG_COUNT), dim3(256), 0, stream,
                       x, emb, z, cd, Le, B2, Den, out);
}